// Round 4
// baseline (663.861 us; speedup 1.0000x reference)
//
#include <hip/hip_runtime.h>
#include <hip/hip_bf16.h>

#define T_TOK   16384
#define DDIM    2048
#define HDIM    4096
#define NEXP    8
#define BM      256
#define BN      256
#define BK      32
#define NKT     (DDIM / BK)     // 64 K-tiles
#define NBAND   (HDIM / BN)     // 16 N-bands
#define MAX_TILES 72
#define KTILE_BYTES 16384       // 256 rows x 32 k x 2B
#define NBLK    (MAX_TILES * NBAND)   // 1152, % 8 == 0

typedef __attribute__((ext_vector_type(4))) float f32x4;
typedef __attribute__((ext_vector_type(8))) __bf16 bf16x8;

// ---- workspace layout ----
#define WS_TILE_EXPERT 16
#define WS_TILE_START  (16 + MAX_TILES)
#define WS_TILE_NROWS  (16 + 2*MAX_TILES)
#define WS_ROW_IDS     1024
#define WS_APACK_OFF   131072ULL
#define WS_APACK_SZ    ((size_t)MAX_TILES * NKT * KTILE_BYTES)
#define WS_WB_OFF      (WS_APACK_OFF + WS_APACK_SZ)
#define WS_WB_SZ       ((size_t)NEXP * NBAND * NKT * KTILE_BYTES)

// Swizzle: 16B-quad q of row r stored at quad (q ^ ((r>>1)&3)) within the row's
// 64B. Frag reads hit all 8 bank-quads of each 128B pair exactly once (R3: 0 conflicts).

__device__ __forceinline__ void gload16(const void* g, void* l) {
    __builtin_amdgcn_global_load_lds(
        (const __attribute__((address_space(1))) void*)g,
        (__attribute__((address_space(3))) void*)l, 16, 0, 0);
}

__global__ void routing_kernel(const int* __restrict__ topk_ids, int* __restrict__ wsi) {
    __shared__ int cnt[NEXP];
    __shared__ int base[NEXP];
    int tid = threadIdx.x;
    if (tid < NEXP) cnt[tid] = 0;
    __syncthreads();
    for (int i = tid; i < T_TOK; i += blockDim.x)
        atomicAdd(&cnt[topk_ids[i]], 1);
    __syncthreads();
    if (tid == 0) {
        int acc = 0, nt = 0;
        for (int e = 0; e < NEXP; ++e) {
            base[e] = acc;
            int c = cnt[e];
            for (int off = 0; off < c; off += BM) {
                wsi[WS_TILE_EXPERT + nt] = e;
                wsi[WS_TILE_START + nt]  = acc + off;
                wsi[WS_TILE_NROWS + nt]  = (c - off < BM) ? (c - off) : BM;
                nt++;
            }
            acc += c;
        }
        wsi[0] = nt;
    }
    __syncthreads();
    if (tid < NEXP) cnt[tid] = base[tid];
    __syncthreads();
    for (int i = tid; i < T_TOK; i += blockDim.x) {
        int pos = atomicAdd(&cnt[topk_ids[i]], 1);
        wsi[WS_ROW_IDS + pos] = i;
    }
}

__global__ __launch_bounds__(256)
void pack_w_kernel(const float* __restrict__ W, unsigned char* __restrict__ wb) {
    long long u = (long long)blockIdx.x * 256 + threadIdx.x;
    int n  = (int)(u % HDIM);
    int kt = (int)((u / HDIM) % NKT);
    int e  = (int)(u / ((long long)HDIM * NKT));
    const float* src = W + ((size_t)e * DDIM + (size_t)kt * BK) * HDIM + n;
    int band = n >> 8;
    int row  = n & 255;
    unsigned char* dst = wb + (((size_t)(e * NBAND + band) * NKT + kt) * KTILE_BYTES) + row * 64;
    const int qsw = (row >> 1) & 3;
    #pragma unroll
    for (int q = 0; q < 4; ++q) {
        bf16x8 h;
        #pragma unroll
        for (int j = 0; j < 8; ++j)
            h[j] = (__bf16)src[(size_t)(q * 8 + j) * HDIM];
        *reinterpret_cast<bf16x8*>(dst + ((q ^ qsw) << 4)) = h;
    }
}

__global__ __launch_bounds__(256)
void pack_a_kernel(const float* __restrict__ X, const int* __restrict__ wsi,
                   unsigned char* __restrict__ apack) {
    const int tile = blockIdx.x;
    if (tile >= wsi[0]) return;
    const int kt = blockIdx.y;
    const int rstart = wsi[WS_TILE_START + tile];
    const int nrows  = wsi[WS_TILE_NROWS + tile];
    const int r = threadIdx.x;
    unsigned char* dst = apack + ((size_t)tile * NKT + kt) * KTILE_BYTES + r * 64;
    const int qsw = (r >> 1) & 3;
    bf16x8 v0, v1, v2, v3;
    if (r < nrows) {
        int slot = wsi[WS_ROW_IDS + rstart + r];
        const f32x4* p = reinterpret_cast<const f32x4*>(X + (size_t)slot * DDIM + kt * BK);
        f32x4 f[8];
        #pragma unroll
        for (int i = 0; i < 8; ++i) f[i] = p[i];
        #pragma unroll
        for (int j = 0; j < 4; ++j) { v0[j] = (__bf16)f[0][j]; v0[4+j] = (__bf16)f[1][j]; }
        #pragma unroll
        for (int j = 0; j < 4; ++j) { v1[j] = (__bf16)f[2][j]; v1[4+j] = (__bf16)f[3][j]; }
        #pragma unroll
        for (int j = 0; j < 4; ++j) { v2[j] = (__bf16)f[4][j]; v2[4+j] = (__bf16)f[5][j]; }
        #pragma unroll
        for (int j = 0; j < 4; ++j) { v3[j] = (__bf16)f[6][j]; v3[4+j] = (__bf16)f[7][j]; }
    } else {
        #pragma unroll
        for (int j = 0; j < 8; ++j) { v0[j]=(__bf16)0.f; v1[j]=(__bf16)0.f; v2[j]=(__bf16)0.f; v3[j]=(__bf16)0.f; }
    }
    *reinterpret_cast<bf16x8*>(dst + ((0 ^ qsw) << 4)) = v0;
    *reinterpret_cast<bf16x8*>(dst + ((1 ^ qsw) << 4)) = v1;
    *reinterpret_cast<bf16x8*>(dst + ((2 ^ qsw) << 4)) = v2;
    *reinterpret_cast<bf16x8*>(dst + ((3 ^ qsw) << 4)) = v3;
}

// ---- 4-buffer-ring counted-vmcnt grouped GEMM, 256x256 tile, 8 waves ----
__device__ __forceinline__ void compute_ktile(const unsigned char* bufc,
                                              int abase, int bbase,
                                              f32x4 acc[8][4]) {
    bf16x8 afr[8], bfr[4];
    #pragma unroll
    for (int mf = 0; mf < 8; ++mf)
        afr[mf] = *reinterpret_cast<const bf16x8*>(bufc + abase + mf * 1024);
    #pragma unroll
    for (int nf = 0; nf < 4; ++nf)
        bfr[nf] = *reinterpret_cast<const bf16x8*>(bufc + bbase + nf * 1024);
    __builtin_amdgcn_s_setprio(1);
    #pragma unroll
    for (int mf = 0; mf < 8; ++mf)
        #pragma unroll
        for (int nf = 0; nf < 4; ++nf)
            acc[mf][nf] = __builtin_amdgcn_mfma_f32_16x16x32_bf16(afr[mf], bfr[nf], acc[mf][nf], 0, 0, 0);
    __builtin_amdgcn_s_setprio(0);
}

__global__ __launch_bounds__(512, 2)
void gemm_fast(const unsigned char* __restrict__ apack,
               const unsigned char* __restrict__ wb,
               const float* __restrict__ topk_weight,
               const int* __restrict__ wsi,
               float* __restrict__ Out) {
    const int id  = blockIdx.x;
    const int swz = (id & 7) * (NBLK / 8) + (id >> 3);   // chunked XCD swizzle
    const int tile = swz / NBAND;    // tile-major: co-resident blocks share A tile
    const int band = swz % NBAND;
    if (tile >= wsi[0]) return;
    const int e      = wsi[WS_TILE_EXPERT + tile];
    const int rstart = wsi[WS_TILE_START + tile];
    const int nrows  = wsi[WS_TILE_NROWS + tile];

    extern __shared__ unsigned char smem[];   // 4 bufs x 32KB = 128KB

    const int t    = threadIdx.x;
    const int lane = t & 63;
    const int wid  = t >> 6;
    const int wm   = wid >> 2;
    const int wn   = wid & 3;
    const int r16  = lane & 15;
    const int c16  = lane >> 4;

    const unsigned char* ag = apack + (size_t)tile * NKT * KTILE_BYTES + t * 16;
    const unsigned char* bg = wb + ((size_t)(e * NBAND + band) * NKT) * KTILE_BYTES + t * 16;
    const int ldst = wid * 1024;

    const int qswz  = c16 ^ ((r16 >> 1) & 3);
    const int abase = (wm * 128 + r16) * 64 + (qswz << 4);
    const int bbase = 16384 + (wn * 64 + r16) * 64 + (qswz << 4);

    f32x4 acc[8][4];
    #pragma unroll
    for (int i = 0; i < 8; ++i)
        #pragma unroll
        for (int j = 0; j < 4; ++j)
            acc[i][j] = (f32x4)(0.0f);

#define STAGE(kt, boff) do {                                                         \
    gload16(ag + (size_t)(kt) * KTILE_BYTES,         smem + (boff) + ldst);          \
    gload16(ag + (size_t)(kt) * KTILE_BYTES + 8192,  smem + (boff) + 8192 + ldst);   \
    gload16(bg + (size_t)(kt) * KTILE_BYTES,         smem + (boff) + 16384 + ldst);  \
    gload16(bg + (size_t)(kt) * KTILE_BYTES + 8192,  smem + (boff) + 24576 + ldst);  \
} while (0)

    // prologue: stage tiles 0,1,2 (12 loads); wait tile 0 (keep 8 in flight)
    STAGE(0, 0);
    STAGE(1, 32768);
    STAGE(2, 65536);
    asm volatile("s_waitcnt vmcnt(8)" ::: "memory");
    __builtin_amdgcn_s_barrier();
    __builtin_amdgcn_sched_barrier(0);

    #pragma unroll 1
    for (int kt = 0; kt < NKT - 3; ++kt) {
        STAGE(kt + 3, ((kt + 3) & 3) * 32768);     // overwrites tile kt-1's buf (safe: read-done)
        compute_ktile(smem + (kt & 3) * 32768, abase, bbase, acc);
        // oldest 4 outstanding = tile kt+1 must land; tiles kt+2, kt+3 stay in flight
        asm volatile("s_waitcnt vmcnt(8)" ::: "memory");
        __builtin_amdgcn_s_barrier();
        __builtin_amdgcn_sched_barrier(0);
    }
    // kt = NKT-3
    compute_ktile(smem + ((NKT - 3) & 3) * 32768, abase, bbase, acc);
    asm volatile("s_waitcnt vmcnt(4)" ::: "memory");
    __builtin_amdgcn_s_barrier();
    __builtin_amdgcn_sched_barrier(0);
    // kt = NKT-2
    compute_ktile(smem + ((NKT - 2) & 3) * 32768, abase, bbase, acc);
    asm volatile("s_waitcnt vmcnt(0)" ::: "memory");
    __builtin_amdgcn_s_barrier();
    __builtin_amdgcn_sched_barrier(0);
    // kt = NKT-1
    compute_ktile(smem + ((NKT - 1) & 3) * 32768, abase, bbase, acc);
#undef STAGE

    // epilogue: weighted atomic scatter-add (each out element gets exactly 2 adds)
    const int col0 = band * BN + wn * 64 + r16;
    #pragma unroll
    for (int mf = 0; mf < 8; ++mf) {
        const int rbase = wm * 128 + mf * 16 + c16 * 4;
        #pragma unroll
        for (int i = 0; i < 4; ++i) {
            int rl = rbase + i;
            if (rl < nrows) {
                int slot = wsi[WS_ROW_IDS + rstart + rl];
                float wt = topk_weight[slot];
                float* orow = Out + (size_t)(slot >> 1) * HDIM + col0;
                #pragma unroll
                for (int nf = 0; nf < 4; ++nf)
                    atomicAdd(orow + nf * 16, acc[mf][nf][i] * wt);
            }
        }
    }
}

extern "C" void kernel_launch(void* const* d_in, const int* in_sizes, int n_in,
                              void* d_out, int out_size, void* d_ws, size_t ws_size,
                              hipStream_t stream) {
    const float* X   = (const float*)d_in[0];
    const float* W   = (const float*)d_in[1];
    const float* wgt = (const float*)d_in[2];
    const int*   ids = (const int*)d_in[3];
    float* Out = (float*)d_out;
    int*   wsi = (int*)d_ws;
    unsigned char* apack = (unsigned char*)d_ws + WS_APACK_OFF;
    unsigned char* wb    = (unsigned char*)d_ws + WS_WB_OFF;

    hipMemsetAsync(d_out, 0, (size_t)out_size * sizeof(float), stream);
    routing_kernel<<<1, 256, 0, stream>>>(ids, wsi);
    pack_w_kernel<<<(NEXP * NKT * HDIM) / 256, 256, 0, stream>>>(W, wb);
    dim3 agrid(MAX_TILES, NKT, 1);
    pack_a_kernel<<<agrid, 256, 0, stream>>>(X, wsi, apack);
    gemm_fast<<<NBLK, 512, 131072, stream>>>(apack, wb, wgt, wsi, Out);
}